// Round 2
// baseline (1405.018 us; speedup 1.0000x reference)
//
#include <hip/hip_runtime.h>
#include <hip/hip_fp16.h>
#include <hip/hip_cooperative_groups.h>

namespace cg = cooperative_groups;

// GCN: 4x GCNConv(128->128, sym norm, self-loops) + FC(128->32) + global mean pool.
// R13->R14: pipeline was DISPATCH-OVERHEAD-BOUND (~10-13us x 12 dispatches fits the
// 286us residual after ~60us of kernel work + 45us harness poison). Now 2 dispatches:
// [collapse] + [cooperative mega-kernel] with 10 grid.sync()s replacing 10 kernel
// boundaries. Also: csr entry 8B->4B (ushort src + fp16 weight, rows padded to x4 so
// a quarter-wave loads 4 edges in ONE aligned uint4), rank-based fill (hist's
// atomicAdd return = slot, no cursor atomics), padded row_off[n+1]-row_off[n] kills
// the indeg load in agg.

#define N_NODES 50000
#define N_EDGES 600000
#define D 128
#define D_OUT 32
#define N_GRAPHS 64
#define SCAN_B 1024
#define N_SCAN_BLOCKS 49          // ceil(50000/1024)
#define GEMM_TILES 782            // ceil(50000/64)
#define AGG_GROUPS 12500          // 50000/4
#define MEGA_GRID 1024            // 4 blocks/CU x 256 CU, guaranteed by launch_bounds

typedef short short8 __attribute__((ext_vector_type(8)));
typedef float floatx4 __attribute__((ext_vector_type(4)));

__device__ inline unsigned bf16rne(float a) {
    unsigned u = __float_as_uint(a);
    return (u + 0x7fffu + ((u >> 16) & 1u)) >> 16;
}
__device__ inline unsigned bf16pair(float a, float b) {
    return bf16rne(a) | (bf16rne(b) << 16);
}

// ---------------- weight collapse (separate kernel, 1 block) ----------------
// y = A(A(A(A z + 1c1) + 1c2) + 1c3) + 1c4, z = x @ Wc.
// Wc = W1W2W3W4 fcW; c1=b1@S1, c2=b2@S2, c3=b3@S3, c4=b4@fcW+fcb.
__global__ __launch_bounds__(1024) void collapse_kernel(
        const float* __restrict__ W1, const float* __restrict__ W2,
        const float* __restrict__ W3, const float* __restrict__ W4,
        const float* __restrict__ fcW, const float* __restrict__ fcb,
        const float* __restrict__ b1, const float* __restrict__ b2,
        const float* __restrict__ b3, const float* __restrict__ b4,
        unsigned short* __restrict__ WcT, float* __restrict__ cvec) {
    __shared__ float Sa[128][33];
    __shared__ float Sb[128][33];
    int t = threadIdx.x;
    int i = t >> 3;          // 0..127 output row
    int j4 = (t & 7) * 4;    // output col group of 4

    for (int idx = t; idx < 4096; idx += 1024) Sa[idx >> 5][idx & 31] = fcW[idx];
    __syncthreads();
    if (t < 32) {  // c4 = b4 @ fcW + fcb
        float acc = fcb[t];
        for (int k = 0; k < 128; ++k) acc += b4[k] * Sa[k][t];
        cvec[96 + t] = acc;
    }
    {   // Sb = S3 = W4 @ fcW
        float a0 = 0.f, a1 = 0.f, a2 = 0.f, a3 = 0.f;
        for (int k = 0; k < 128; ++k) {
            float w = W4[i * 128 + k];
            a0 += w * Sa[k][j4 + 0]; a1 += w * Sa[k][j4 + 1];
            a2 += w * Sa[k][j4 + 2]; a3 += w * Sa[k][j4 + 3];
        }
        Sb[i][j4 + 0] = a0; Sb[i][j4 + 1] = a1; Sb[i][j4 + 2] = a2; Sb[i][j4 + 3] = a3;
    }
    __syncthreads();
    if (t < 32) {  // c3 = b3 @ S3
        float acc = 0.f;
        for (int k = 0; k < 128; ++k) acc += b3[k] * Sb[k][t];
        cvec[64 + t] = acc;
    }
    {   // Sa = S2 = W3 @ S3
        float a0 = 0.f, a1 = 0.f, a2 = 0.f, a3 = 0.f;
        for (int k = 0; k < 128; ++k) {
            float w = W3[i * 128 + k];
            a0 += w * Sb[k][j4 + 0]; a1 += w * Sb[k][j4 + 1];
            a2 += w * Sb[k][j4 + 2]; a3 += w * Sb[k][j4 + 3];
        }
        Sa[i][j4 + 0] = a0; Sa[i][j4 + 1] = a1; Sa[i][j4 + 2] = a2; Sa[i][j4 + 3] = a3;
    }
    __syncthreads();
    if (t < 32) {  // c2 = b2 @ S2
        float acc = 0.f;
        for (int k = 0; k < 128; ++k) acc += b2[k] * Sa[k][t];
        cvec[32 + t] = acc;
    }
    {   // Sb = S1 = W2 @ S2
        float a0 = 0.f, a1 = 0.f, a2 = 0.f, a3 = 0.f;
        for (int k = 0; k < 128; ++k) {
            float w = W2[i * 128 + k];
            a0 += w * Sa[k][j4 + 0]; a1 += w * Sa[k][j4 + 1];
            a2 += w * Sa[k][j4 + 2]; a3 += w * Sa[k][j4 + 3];
        }
        Sb[i][j4 + 0] = a0; Sb[i][j4 + 1] = a1; Sb[i][j4 + 2] = a2; Sb[i][j4 + 3] = a3;
    }
    __syncthreads();
    if (t < 32) {  // c1 = b1 @ S1
        float acc = 0.f;
        for (int k = 0; k < 128; ++k) acc += b1[k] * Sb[k][t];
        cvec[t] = acc;
    }
    {   // Wc = W1 @ S1 -> WcT[j][k] bf16 (MFMA B layout)
        float a0 = 0.f, a1 = 0.f, a2 = 0.f, a3 = 0.f;
        for (int k = 0; k < 128; ++k) {
            float w = W1[i * 128 + k];
            a0 += w * Sb[k][j4 + 0]; a1 += w * Sb[k][j4 + 1];
            a2 += w * Sb[k][j4 + 2]; a3 += w * Sb[k][j4 + 3];
        }
        WcT[(j4 + 0) * 128 + i] = (unsigned short)bf16rne(a0);
        WcT[(j4 + 1) * 128 + i] = (unsigned short)bf16rne(a1);
        WcT[(j4 + 2) * 128 + i] = (unsigned short)bf16rne(a2);
        WcT[(j4 + 3) * 128 + i] = (unsigned short)bf16rne(a3);
    }
}

// ---------------- mega kernel ----------------

struct MegaArgs {
    const float* x;
    const int* src;
    const int* dst;
    const int* batch;
    const unsigned short* WcT;
    const float* cvec;
    int* indeg;
    unsigned short* rank;
    int* bsum;
    int* row_off;   // padded exclusive scan, length N_NODES+1
    float* dinv;
    unsigned* csr4; // ushort src | (fp16 w)<<16, rows padded to x4 with w=0
    unsigned* buf0;
    unsigned* buf1;
    float* p;
    float* out;
};

// One node per wave; quarter-wave q loads 4 edges per trip as one aligned uint4.
// Pad slots have w=+0.0 (u==0) -> gather row 0, fma x0: no clamps, no divergence.
template <bool FINAL>
__device__ inline void agg_phase(const unsigned* __restrict__ Gb,
                                 const float* __restrict__ bias,
                                 const MegaArgs& A, unsigned* __restrict__ outb,
                                 int wave, int lane) {
    int q = lane >> 4, c = lane & 15;
    const unsigned hm = 0xffff0000u;
    for (int g = blockIdx.x; g < AGG_GROUPS; g += gridDim.x) {
        int n = g * 4 + wave;  // N_NODES % 4 == 0
        float a0 = 0.f, a1 = 0.f;
        int pbeg = A.row_off[n], pend = A.row_off[n + 1];
        for (int e4 = pbeg + (q << 2); e4 < pend; e4 += 16) {
            uint4 cs = *(const uint4*)(A.csr4 + e4);
            unsigned r0 = Gb[(cs.x & 0xffffu) * 16 + c];
            unsigned r1 = Gb[(cs.y & 0xffffu) * 16 + c];
            unsigned r2 = Gb[(cs.z & 0xffffu) * 16 + c];
            unsigned r3 = Gb[(cs.w & 0xffffu) * 16 + c];
            float w0 = __half2float(__ushort_as_half((unsigned short)(cs.x >> 16)));
            float w1 = __half2float(__ushort_as_half((unsigned short)(cs.y >> 16)));
            float w2 = __half2float(__ushort_as_half((unsigned short)(cs.z >> 16)));
            float w3 = __half2float(__ushort_as_half((unsigned short)(cs.w >> 16)));
            a0 += w0 * __uint_as_float(r0 << 16) + w1 * __uint_as_float(r1 << 16) +
                  w2 * __uint_as_float(r2 << 16) + w3 * __uint_as_float(r3 << 16);
            a1 += w0 * __uint_as_float(r0 & hm) + w1 * __uint_as_float(r1 & hm) +
                  w2 * __uint_as_float(r2 & hm) + w3 * __uint_as_float(r3 & hm);
        }
        a0 += __shfl_xor(a0, 16, 64); a0 += __shfl_xor(a0, 32, 64);
        a1 += __shfl_xor(a1, 16, 64); a1 += __shfl_xor(a1, 32, 64);
        if (q == 0) {
            float di = A.dinv[n];
            float sw = di * di;
            unsigned sv = Gb[n * 16 + c];
            a0 += sw * __uint_as_float(sv << 16);
            a1 += sw * __uint_as_float(sv & hm);
            if constexpr (FINAL) {
                ((float2*)A.p)[n * 16 + c] = make_float2(a0, a1);
            } else {
                float2 bb = ((const float2*)bias)[c];
                outb[(size_t)n * 16 + c] = bf16pair(a0 + bb.x, a1 + bb.y);
            }
        }
    }
}

__global__ __launch_bounds__(256, 4) void mega_kernel(MegaArgs A) {
    __shared__ int sdata[257];
    __shared__ unsigned short gtile[4][16 * 32];
    __shared__ float partial[8][32];

    cg::grid_group grid = cg::this_grid();
    int t = threadIdx.x;
    int wave = t >> 6, lane = t & 63;
    int gid = blockIdx.x * 256 + t;
    int gstride = gridDim.x * 256;

    // ---- phase 0: zero indeg ----
    for (int i = gid; i < N_NODES; i += gstride) A.indeg[i] = 0;
    grid.sync();

    // ---- phase 1: histogram + per-edge rank (slot within dst row) ----
    for (int e = gid; e < N_EDGES; e += gstride) {
        int d = A.dst[e];
        A.rank[e] = (unsigned short)atomicAdd(&A.indeg[d], 1);
    }
    grid.sync();

    // ---- phase 2: per-chunk PADDED degree sums ----
    if (blockIdx.x < N_SCAN_BLOCKS) {
        int i0 = blockIdx.x * SCAN_B + t * 4;
        int v0 = (i0 + 0 < N_NODES) ? A.indeg[i0 + 0] : 0;
        int v1 = (i0 + 1 < N_NODES) ? A.indeg[i0 + 1] : 0;
        int v2 = (i0 + 2 < N_NODES) ? A.indeg[i0 + 2] : 0;
        int v3 = (i0 + 3 < N_NODES) ? A.indeg[i0 + 3] : 0;
        sdata[t] = ((v0 + 3) & ~3) + ((v1 + 3) & ~3) + ((v2 + 3) & ~3) + ((v3 + 3) & ~3);
        __syncthreads();
        for (int s = 128; s > 0; s >>= 1) {
            if (t < s) sdata[t] += sdata[t + s];
            __syncthreads();
        }
        if (t == 0) A.bsum[blockIdx.x] = sdata[0];
    }
    grid.sync();

    // ---- phase 3: exclusive scan of padded degrees -> row_off, dinv, pad slots ----
    if (blockIdx.x < N_SCAN_BLOCKS) {
        int blk = blockIdx.x;
        int i0 = blk * SCAN_B + t * 4;
        int v0 = (i0 + 0 < N_NODES) ? A.indeg[i0 + 0] : 0;
        int v1 = (i0 + 1 < N_NODES) ? A.indeg[i0 + 1] : 0;
        int v2 = (i0 + 2 < N_NODES) ? A.indeg[i0 + 2] : 0;
        int v3 = (i0 + 3 < N_NODES) ? A.indeg[i0 + 3] : 0;
        int p0 = (v0 + 3) & ~3, p1 = (v1 + 3) & ~3, p2 = (v2 + 3) & ~3, p3 = (v3 + 3) & ~3;
        int tsum = p0 + p1 + p2 + p3;
        if (t < 64) {
            int v = (t < blk) ? A.bsum[t] : 0;
#pragma unroll
            for (int off = 1; off < 64; off <<= 1) v += __shfl_xor(v, off, 64);
            if (t == 0) sdata[256] = v;
        }
        sdata[t] = tsum;
        __syncthreads();
        for (int off = 1; off < 256; off <<= 1) {
            int add = (t >= off) ? sdata[t - off] : 0;
            __syncthreads();
            sdata[t] += add;
            __syncthreads();
        }
        int base = sdata[256] + sdata[t] - tsum;
        if (i0 + 0 < N_NODES) {
            A.row_off[i0 + 0] = base;
            A.dinv[i0 + 0] = rsqrtf((float)(v0 + 1));
            for (int j = v0; j < p0; ++j) A.csr4[base + j] = 0u;
        }
        int b1_ = base + p0;
        if (i0 + 1 < N_NODES) {
            A.row_off[i0 + 1] = b1_;
            A.dinv[i0 + 1] = rsqrtf((float)(v1 + 1));
            for (int j = v1; j < p1; ++j) A.csr4[b1_ + j] = 0u;
        }
        int b2_ = b1_ + p1;
        if (i0 + 2 < N_NODES) {
            A.row_off[i0 + 2] = b2_;
            A.dinv[i0 + 2] = rsqrtf((float)(v2 + 1));
            for (int j = v2; j < p2; ++j) A.csr4[b2_ + j] = 0u;
        }
        int b3_ = b2_ + p2;
        if (i0 + 3 < N_NODES) {
            A.row_off[i0 + 3] = b3_;
            A.dinv[i0 + 3] = rsqrtf((float)(v3 + 1));
            for (int j = v3; j < p3; ++j) A.csr4[b3_ + j] = 0u;
        }
        if (i0 + 3 == N_NODES - 1) A.row_off[N_NODES] = b3_ + p3;
    }
    grid.sync();

    // ---- phase 4: fill csr (no atomics: rank from phase 1) ----
    for (int e = gid; e < N_EDGES; e += gstride) {
        int d = A.dst[e], s = A.src[e];
        float w = A.dinv[s] * A.dinv[d];
        unsigned hb = (unsigned)__half_as_ushort(__float2half_rn(w));
        A.csr4[A.row_off[d] + (int)A.rank[e]] = (unsigned)s | (hb << 16);
    }
    grid.sync();

    // ---- phase 5: z = x @ Wc (f32 -> bf16 MFMA, 32 cols) -> buf0 ----
    for (int tb = blockIdx.x; tb < GEMM_TILES; tb += gridDim.x) {
        int row0 = tb * 64 + wave * 16;
        int lm = lane & 15, lg = lane >> 4;
        int arow = row0 + lm;
        if (arow >= N_NODES) arow = N_NODES - 1;
        const float4* Arow = (const float4*)(A.x + (size_t)arow * 128);
        short8 a[4];
#pragma unroll
        for (int kc = 0; kc < 4; ++kc) {
            float4 f0 = Arow[kc * 8 + lg * 2];
            float4 f1 = Arow[kc * 8 + lg * 2 + 1];
            union { short8 s; uint4 u; } cvt;
            cvt.u = make_uint4(bf16pair(f0.x, f0.y), bf16pair(f0.z, f0.w),
                               bf16pair(f1.x, f1.y), bf16pair(f1.z, f1.w));
            a[kc] = cvt.s;
        }
        floatx4 acc[2];
#pragma unroll
        for (int i = 0; i < 2; ++i) acc[i] = (floatx4){0.f, 0.f, 0.f, 0.f};
#pragma unroll
        for (int nt = 0; nt < 2; ++nt) {
            const short8* Brow = (const short8*)(A.WcT + (size_t)(nt * 16 + lm) * 128);
#pragma unroll
            for (int kc = 0; kc < 4; ++kc)
                acc[nt] = __builtin_amdgcn_mfma_f32_16x16x32_bf16(a[kc], Brow[kc * 4 + lg],
                                                                  acc[nt], 0, 0, 0);
        }
        unsigned short* T = gtile[wave];
#pragma unroll
        for (int nt = 0; nt < 2; ++nt)
#pragma unroll
            for (int r = 0; r < 4; ++r)
                T[(lg * 4 + r) * 32 + nt * 16 + lm] = (unsigned short)bf16rne(acc[nt][r]);
        __syncthreads();
        int rr = lane >> 2, cseg = lane & 3;
        int orow = row0 + rr;
        uint4 v = *(const uint4*)&T[rr * 32 + cseg * 8];
        if (orow < N_NODES) ((uint4*)A.buf0)[(size_t)orow * 4 + cseg] = v;
        __syncthreads();
    }
    grid.sync();

    // ---- phases 6-9: four propagations ----
    agg_phase<false>(A.buf0, A.cvec + 0, A, A.buf1, wave, lane);
    grid.sync();
    agg_phase<false>(A.buf1, A.cvec + 32, A, A.buf0, wave, lane);
    grid.sync();
    agg_phase<false>(A.buf0, A.cvec + 64, A, A.buf1, wave, lane);
    grid.sync();
    agg_phase<true>(A.buf1, nullptr, A, nullptr, wave, lane);
    grid.sync();

    // ---- phase 10: global mean pool + c4 ----
    if (blockIdx.x < N_GRAPHS) {
        int g = blockIdx.x;
        int rg = t >> 5, d = t & 31;
        int lo = 0, hi = N_NODES;
        while (lo < hi) { int m = (lo + hi) >> 1; if (A.batch[m] < g) lo = m + 1; else hi = m; }
        int lo2 = lo, hi2 = N_NODES;
        while (lo2 < hi2) { int m = (lo2 + hi2) >> 1; if (A.batch[m] < g + 1) lo2 = m + 1; else hi2 = m; }
        int cnt = lo2 - lo;
        float acc = 0.f;
        int n = lo + rg;
        for (; n + 24 < lo2; n += 32) {
            float u0 = A.p[n * 32 + d];
            float u1 = A.p[(n + 8) * 32 + d];
            float u2 = A.p[(n + 16) * 32 + d];
            float u3 = A.p[(n + 24) * 32 + d];
            acc += (u0 + u1) + (u2 + u3);
        }
        for (; n < lo2; n += 8) acc += A.p[n * 32 + d];
        partial[rg][d] = acc;
        __syncthreads();
        if (rg == 0) {
            float s = 0.f;
#pragma unroll
            for (int r = 0; r < 8; ++r) s += partial[r][d];
            A.out[g * 32 + d] = (cnt > 0) ? s / (float)cnt + A.cvec[96 + d] : 0.f;
        }
    }
}

// ---------------- launch ----------------

static inline size_t align_up(size_t x) { return (x + 255) & ~(size_t)255; }

extern "C" void kernel_launch(void* const* d_in, const int* in_sizes, int n_in,
                              void* d_out, int out_size, void* d_ws, size_t ws_size,
                              hipStream_t stream) {
    const float* x = (const float*)d_in[0];
    const int* edge_index = (const int*)d_in[1];
    const int* batch = (const int*)d_in[2];
    const float* W1 = (const float*)d_in[3];
    const float* b1 = (const float*)d_in[4];
    const float* W2 = (const float*)d_in[5];
    const float* b2 = (const float*)d_in[6];
    const float* W3 = (const float*)d_in[7];
    const float* b3 = (const float*)d_in[8];
    const float* W4 = (const float*)d_in[9];
    const float* b4 = (const float*)d_in[10];
    const float* fcW = (const float*)d_in[11];
    const float* fcb = (const float*)d_in[12];
    float* out = (float*)d_out;

    const int* src = edge_index;
    const int* dst = edge_index + N_EDGES;

    char* base = (char*)d_ws;
    size_t o = 0;
    unsigned* buf0 = (unsigned*)(base + o);  o = align_up(o + (size_t)N_NODES * D_OUT * 2);
    unsigned* buf1 = (unsigned*)(base + o);  o = align_up(o + (size_t)N_NODES * D_OUT * 2);
    unsigned* csr4 = (unsigned*)(base + o);  o = align_up(o + (size_t)768000 * 4);
    unsigned short* rank = (unsigned short*)(base + o); o = align_up(o + (size_t)N_EDGES * 2);
    int* row_off = (int*)(base + o);         o = align_up(o + (size_t)(N_NODES + 1) * 4);
    int* indeg = (int*)(base + o);           o = align_up(o + (size_t)N_NODES * 4);
    float* dinv = (float*)(base + o);        o = align_up(o + (size_t)N_NODES * 4);
    int* bsum = (int*)(base + o);            o = align_up(o + 256);
    unsigned short* WcT = (unsigned short*)(base + o); o = align_up(o + (size_t)D * D_OUT * 2);
    float* cvec = (float*)(base + o);        o = align_up(o + 128 * 4);
    float* p = (float*)(base + o);           o = align_up(o + (size_t)N_NODES * D_OUT * 4);

    collapse_kernel<<<1, 1024, 0, stream>>>(W1, W2, W3, W4, fcW, fcb, b1, b2, b3, b4,
                                            WcT, cvec);

    MegaArgs A;
    A.x = x; A.src = src; A.dst = dst; A.batch = batch;
    A.WcT = WcT; A.cvec = cvec;
    A.indeg = indeg; A.rank = rank; A.bsum = bsum; A.row_off = row_off;
    A.dinv = dinv; A.csr4 = csr4; A.buf0 = buf0; A.buf1 = buf1;
    A.p = p; A.out = out;
    void* kargs[] = {&A};
    hipLaunchCooperativeKernel((void*)mega_kernel, dim3(MEGA_GRID), dim3(256), kargs,
                               0, stream);
}

// Round 5
// 253.044 us; speedup vs baseline: 5.5525x; 5.5525x over previous
//
#include <hip/hip_runtime.h>
#include <hip/hip_fp16.h>

// GCN: 4x GCNConv(128->128, sym norm, self-loops) + FC(128->32) + global mean pool.
// R16->R17: mega-kernel path ABANDONED. R15/R16 failed with bit-identical absmax
// across two different barrier implementations => not a race; evidence fits
// "cooperative launch never ran / never wrote out" (pytest absmax 1.4e-2 == max|ref|
// of zeroed output; bench absmax 468 == poison). Reverting to split dispatches
// (everything below is R13/R14-correctness-verified) with structural dispatch
// reduction 12 -> 9:
//   D1 prep:  blocks 0-48 zero indeg, block 49 = weight collapse (1024 thr)
//   D2 hist:  indeg atomicAdd + per-edge rank (atomic return = csr slot)
//   D3 scan:  FUSED single-dispatch scan: 13 blocks x 4096-node chunks; each block
//             redundantly sums all preceding padded degrees (<=49K ints, L2) as its
//             prefix base -- kills the bsum/scanD two-pass hierarchy
//   D4 fillgemm: blocks 0-781 = z = x@Wc MFMA gemm; blocks 782-3125 = csr fill
//   D5-D8 agg x4: R14-verified 4B-csr (ushort src | fp16 w), x4-padded rows,
//             one uint4 = 4 edge slots per quarter-wave per trip
//   D9 tail:  global mean pool + c4
// Collapsed-linear math (R13): y = A(A(A(A(x@Wc) + 1c1) + 1c2) + 1c3) + 1c4.

#define N_NODES 50000
#define N_EDGES 600000
#define D 128
#define D_OUT 32
#define N_GRAPHS 64
#define CHUNK 4096                 // scan chunk (1024 thr x 4)
#define N_SCAN_BLOCKS 13           // ceil(50000/4096)
#define GEMM_TILES 782             // ceil(50000/64)
#define FILL_BLOCKS 2344           // ceil(600000/256)
#define AGG_GRID 12500             // 50000/4

typedef short short8 __attribute__((ext_vector_type(8)));
typedef float floatx4 __attribute__((ext_vector_type(4)));

__device__ inline unsigned bf16rne(float a) {
    unsigned u = __float_as_uint(a);
    return (u + 0x7fffu + ((u >> 16) & 1u)) >> 16;
}
__device__ inline unsigned bf16pair(float a, float b) {
    return bf16rne(a) | (bf16rne(b) << 16);
}

// ---------------- D1: zero indeg + weight collapse ----------------
__global__ __launch_bounds__(1024) void prep_kernel(
        int* __restrict__ indeg,
        const float* __restrict__ W1, const float* __restrict__ W2,
        const float* __restrict__ W3, const float* __restrict__ W4,
        const float* __restrict__ fcW, const float* __restrict__ fcb,
        const float* __restrict__ b1, const float* __restrict__ b2,
        const float* __restrict__ b3, const float* __restrict__ b4,
        unsigned short* __restrict__ WcT, float* __restrict__ cvec) {
    int t = threadIdx.x;
    if (blockIdx.x < 49) {  // zero indeg
        int i = blockIdx.x * 1024 + t;
        if (i < N_NODES) indeg[i] = 0;
        return;
    }
    // block 49: collapse. Wc = W1W2W3W4 fcW; c1=b1@S1, c2=b2@S2, c3=b3@S3,
    // c4=b4@fcW+fcb. All fp32; WcT stored bf16 [32][128] (MFMA B layout).
    __shared__ float Sa[128][33];
    __shared__ float Sb[128][33];
    int i = t >> 3;          // 0..127 output row
    int j4 = (t & 7) * 4;    // output col group of 4

    for (int idx = t; idx < 4096; idx += 1024) Sa[idx >> 5][idx & 31] = fcW[idx];
    __syncthreads();
    if (t < 32) {  // c4
        float acc = fcb[t];
        for (int k = 0; k < 128; ++k) acc += b4[k] * Sa[k][t];
        cvec[96 + t] = acc;
    }
    {   // Sb = S3 = W4 @ fcW
        float a0 = 0.f, a1 = 0.f, a2 = 0.f, a3 = 0.f;
        for (int k = 0; k < 128; ++k) {
            float w = W4[i * 128 + k];
            a0 += w * Sa[k][j4 + 0]; a1 += w * Sa[k][j4 + 1];
            a2 += w * Sa[k][j4 + 2]; a3 += w * Sa[k][j4 + 3];
        }
        Sb[i][j4 + 0] = a0; Sb[i][j4 + 1] = a1; Sb[i][j4 + 2] = a2; Sb[i][j4 + 3] = a3;
    }
    __syncthreads();
    if (t < 32) {  // c3
        float acc = 0.f;
        for (int k = 0; k < 128; ++k) acc += b3[k] * Sb[k][t];
        cvec[64 + t] = acc;
    }
    {   // Sa = S2 = W3 @ S3
        float a0 = 0.f, a1 = 0.f, a2 = 0.f, a3 = 0.f;
        for (int k = 0; k < 128; ++k) {
            float w = W3[i * 128 + k];
            a0 += w * Sb[k][j4 + 0]; a1 += w * Sb[k][j4 + 1];
            a2 += w * Sb[k][j4 + 2]; a3 += w * Sb[k][j4 + 3];
        }
        Sa[i][j4 + 0] = a0; Sa[i][j4 + 1] = a1; Sa[i][j4 + 2] = a2; Sa[i][j4 + 3] = a3;
    }
    __syncthreads();
    if (t < 32) {  // c2
        float acc = 0.f;
        for (int k = 0; k < 128; ++k) acc += b2[k] * Sa[k][t];
        cvec[32 + t] = acc;
    }
    {   // Sb = S1 = W2 @ S2
        float a0 = 0.f, a1 = 0.f, a2 = 0.f, a3 = 0.f;
        for (int k = 0; k < 128; ++k) {
            float w = W2[i * 128 + k];
            a0 += w * Sa[k][j4 + 0]; a1 += w * Sa[k][j4 + 1];
            a2 += w * Sa[k][j4 + 2]; a3 += w * Sa[k][j4 + 3];
        }
        Sb[i][j4 + 0] = a0; Sb[i][j4 + 1] = a1; Sb[i][j4 + 2] = a2; Sb[i][j4 + 3] = a3;
    }
    __syncthreads();
    if (t < 32) {  // c1
        float acc = 0.f;
        for (int k = 0; k < 128; ++k) acc += b1[k] * Sb[k][t];
        cvec[t] = acc;
    }
    {   // Wc = W1 @ S1 -> WcT
        float a0 = 0.f, a1 = 0.f, a2 = 0.f, a3 = 0.f;
        for (int k = 0; k < 128; ++k) {
            float w = W1[i * 128 + k];
            a0 += w * Sb[k][j4 + 0]; a1 += w * Sb[k][j4 + 1];
            a2 += w * Sb[k][j4 + 2]; a3 += w * Sb[k][j4 + 3];
        }
        WcT[(j4 + 0) * 128 + i] = (unsigned short)bf16rne(a0);
        WcT[(j4 + 1) * 128 + i] = (unsigned short)bf16rne(a1);
        WcT[(j4 + 2) * 128 + i] = (unsigned short)bf16rne(a2);
        WcT[(j4 + 3) * 128 + i] = (unsigned short)bf16rne(a3);
    }
}

// ---------------- D2: histogram + per-edge rank ----------------
__global__ void hist_kernel(const int* __restrict__ dst, int* __restrict__ indeg,
                            unsigned short* __restrict__ rank) {
    int e = blockIdx.x * blockDim.x + threadIdx.x;
    if (e < N_EDGES) rank[e] = (unsigned short)atomicAdd(&indeg[dst[e]], 1);
}

// ---------------- D3: fused scan (redundant prefix) ----------------
// Block b handles nodes [b*4096, ...). Prefix base = sum of PADDED degrees of all
// preceding nodes, computed directly (<= 49152 ints, L2-resident). Then a local
// 1024-wide LDS scan. Writes row_off, dinv, and zero-fills pad slots in csr4.
__global__ __launch_bounds__(1024) void scan_kernel(const int* __restrict__ indeg,
                                                    int* __restrict__ row_off,
                                                    float* __restrict__ dinv,
                                                    unsigned* __restrict__ csr4) {
    __shared__ int sdata[1024];
    __shared__ int pre_total;
    int b = blockIdx.x, t = threadIdx.x;

    // prefix over preceding region (always < 50000, aligned int4)
    int acc = 0;
    for (int j = t * 4; j < b * CHUNK; j += CHUNK) {
        int4 v = *(const int4*)(indeg + j);
        acc += ((v.x + 3) & ~3) + ((v.y + 3) & ~3) + ((v.z + 3) & ~3) + ((v.w + 3) & ~3);
    }
    sdata[t] = acc;
    __syncthreads();
    for (int s = 512; s > 0; s >>= 1) {
        if (t < s) sdata[t] += sdata[t + s];
        __syncthreads();
    }
    if (t == 0) pre_total = sdata[0];
    __syncthreads();

    // local scan of this block's chunk
    int i0 = b * CHUNK + t * 4;
    int v0 = (i0 + 0 < N_NODES) ? indeg[i0 + 0] : 0;
    int v1 = (i0 + 1 < N_NODES) ? indeg[i0 + 1] : 0;
    int v2 = (i0 + 2 < N_NODES) ? indeg[i0 + 2] : 0;
    int v3 = (i0 + 3 < N_NODES) ? indeg[i0 + 3] : 0;
    int p0 = (v0 + 3) & ~3, p1 = (v1 + 3) & ~3, p2 = (v2 + 3) & ~3, p3 = (v3 + 3) & ~3;
    int tsum = p0 + p1 + p2 + p3;
    sdata[t] = tsum;
    __syncthreads();
    for (int off = 1; off < 1024; off <<= 1) {
        int add = (t >= off) ? sdata[t - off] : 0;
        __syncthreads();
        sdata[t] += add;
        __syncthreads();
    }
    int base = pre_total + sdata[t] - tsum;

    if (i0 + 0 < N_NODES) {
        row_off[i0 + 0] = base;
        dinv[i0 + 0] = rsqrtf((float)(v0 + 1));
        for (int j = v0; j < p0; ++j) csr4[base + j] = 0u;
    }
    int b1_ = base + p0;
    if (i0 + 1 < N_NODES) {
        row_off[i0 + 1] = b1_;
        dinv[i0 + 1] = rsqrtf((float)(v1 + 1));
        for (int j = v1; j < p1; ++j) csr4[b1_ + j] = 0u;
    }
    int b2_ = b1_ + p1;
    if (i0 + 2 < N_NODES) {
        row_off[i0 + 2] = b2_;
        dinv[i0 + 2] = rsqrtf((float)(v2 + 1));
        for (int j = v2; j < p2; ++j) csr4[b2_ + j] = 0u;
    }
    int b3_ = b2_ + p2;
    if (i0 + 3 < N_NODES) {
        row_off[i0 + 3] = b3_;
        dinv[i0 + 3] = rsqrtf((float)(v3 + 1));
        for (int j = v3; j < p3; ++j) csr4[b3_ + j] = 0u;
    }
    if (i0 + 3 == N_NODES - 1) row_off[N_NODES] = b3_ + p3;
}

// ---------------- D4: gemm (blocks 0..781) + fill (blocks 782..3125) ----------------
__global__ __launch_bounds__(256) void fillgemm_kernel(
        const float* __restrict__ x, const unsigned short* __restrict__ WcT,
        uint4* __restrict__ outb,
        const int* __restrict__ src, const int* __restrict__ dst,
        const int* __restrict__ row_off, const unsigned short* __restrict__ rank,
        const float* __restrict__ dinv, unsigned* __restrict__ csr4) {
    __shared__ unsigned short tile[4][16 * 32];
    int t = threadIdx.x;
    if (blockIdx.x >= GEMM_TILES) {  // fill
        int e = (blockIdx.x - GEMM_TILES) * 256 + t;
        if (e < N_EDGES) {
            int d = dst[e], s = src[e];
            float w = dinv[s] * dinv[d];
            unsigned hb = (unsigned)__half_as_ushort(__float2half_rn(w));
            csr4[row_off[d] + (int)rank[e]] = (unsigned)s | (hb << 16);
        }
        return;
    }
    // z = x @ Wc (f32 A -> bf16 MFMA, 32 cols)
    int wave = t >> 6, lane = t & 63;
    int row0 = blockIdx.x * 64 + wave * 16;
    int lm = lane & 15, lg = lane >> 4;
    int arow = row0 + lm;
    if (arow >= N_NODES) arow = N_NODES - 1;
    const float4* Arow = (const float4*)(x + (size_t)arow * 128);
    short8 a[4];
#pragma unroll
    for (int kc = 0; kc < 4; ++kc) {
        float4 f0 = Arow[kc * 8 + lg * 2];
        float4 f1 = Arow[kc * 8 + lg * 2 + 1];
        union { short8 s; uint4 u; } cvt;
        cvt.u = make_uint4(bf16pair(f0.x, f0.y), bf16pair(f0.z, f0.w),
                           bf16pair(f1.x, f1.y), bf16pair(f1.z, f1.w));
        a[kc] = cvt.s;
    }
    floatx4 acc[2];
#pragma unroll
    for (int i = 0; i < 2; ++i) acc[i] = (floatx4){0.f, 0.f, 0.f, 0.f};
#pragma unroll
    for (int nt = 0; nt < 2; ++nt) {
        const short8* Brow = (const short8*)(WcT + (size_t)(nt * 16 + lm) * 128);
#pragma unroll
        for (int kc = 0; kc < 4; ++kc)
            acc[nt] = __builtin_amdgcn_mfma_f32_16x16x32_bf16(a[kc], Brow[kc * 4 + lg],
                                                              acc[nt], 0, 0, 0);
    }
    unsigned short* T = tile[wave];
#pragma unroll
    for (int nt = 0; nt < 2; ++nt)
#pragma unroll
        for (int r = 0; r < 4; ++r)
            T[(lg * 4 + r) * 32 + nt * 16 + lm] = (unsigned short)bf16rne(acc[nt][r]);
    __syncthreads();
    int rr = lane >> 2, cseg = lane & 3;
    int orow = row0 + rr;
    uint4 v = *(const uint4*)&T[rr * 32 + cseg * 8];
    if (orow < N_NODES) outb[(size_t)orow * 4 + cseg] = v;
}

// ---------------- D5-D8: 32-dim aggregation (R14-verified body) ----------------
// One node/wave; quarter-wave q loads 4 edges as one aligned uint4 per trip.
// Pad slots: w=+0.0 (u==0) -> gather row 0, fma x0. No clamps, no divergence.
template <bool FINAL>
__global__ __launch_bounds__(256) void agg_kernel(const unsigned* __restrict__ Gb,
                                                  const float* __restrict__ bias,
                                                  const float* __restrict__ dinv,
                                                  const int* __restrict__ row_off,
                                                  const unsigned* __restrict__ csr4,
                                                  unsigned* __restrict__ outb,
                                                  float* __restrict__ p) {
    int wave = threadIdx.x >> 6;
    int lane = threadIdx.x & 63;
    int n = blockIdx.x * 4 + wave;  // N_NODES % 4 == 0
    int q = lane >> 4, c = lane & 15;
    const unsigned hm = 0xffff0000u;

    float a0 = 0.f, a1 = 0.f;
    int pbeg = row_off[n], pend = row_off[n + 1];
    for (int e4 = pbeg + (q << 2); e4 < pend; e4 += 16) {
        uint4 cs = *(const uint4*)(csr4 + e4);
        unsigned r0 = Gb[(cs.x & 0xffffu) * 16 + c];
        unsigned r1 = Gb[(cs.y & 0xffffu) * 16 + c];
        unsigned r2 = Gb[(cs.z & 0xffffu) * 16 + c];
        unsigned r3 = Gb[(cs.w & 0xffffu) * 16 + c];
        float w0 = __half2float(__ushort_as_half((unsigned short)(cs.x >> 16)));
        float w1 = __half2float(__ushort_as_half((unsigned short)(cs.y >> 16)));
        float w2 = __half2float(__ushort_as_half((unsigned short)(cs.z >> 16)));
        float w3 = __half2float(__ushort_as_half((unsigned short)(cs.w >> 16)));
        a0 += w0 * __uint_as_float(r0 << 16) + w1 * __uint_as_float(r1 << 16) +
              w2 * __uint_as_float(r2 << 16) + w3 * __uint_as_float(r3 << 16);
        a1 += w0 * __uint_as_float(r0 & hm) + w1 * __uint_as_float(r1 & hm) +
              w2 * __uint_as_float(r2 & hm) + w3 * __uint_as_float(r3 & hm);
    }
    a0 += __shfl_xor(a0, 16, 64); a0 += __shfl_xor(a0, 32, 64);
    a1 += __shfl_xor(a1, 16, 64); a1 += __shfl_xor(a1, 32, 64);
    if (q == 0) {
        float di = dinv[n];
        float sw = di * di;
        unsigned sv = Gb[n * 16 + c];
        a0 += sw * __uint_as_float(sv << 16);
        a1 += sw * __uint_as_float(sv & hm);
        if constexpr (FINAL) {
            ((float2*)p)[n * 16 + c] = make_float2(a0, a1);
        } else {
            float2 bb = ((const float2*)bias)[c];
            outb[(size_t)n * 16 + c] = bf16pair(a0 + bb.x, a1 + bb.y);
        }
    }
}

// ---------------- D9: tail ----------------
__global__ __launch_bounds__(256) void tail_kernel(const float* __restrict__ p,
                                                   const int* __restrict__ batch,
                                                   const float* __restrict__ bc,
                                                   float* __restrict__ out) {
    __shared__ float partial[8][32];
    int g = blockIdx.x;
    int t = threadIdx.x;
    int rg = t >> 5, d = t & 31;
    int lo = 0, hi = N_NODES;
    while (lo < hi) { int m = (lo + hi) >> 1; if (batch[m] < g) lo = m + 1; else hi = m; }
    int lo2 = lo, hi2 = N_NODES;
    while (lo2 < hi2) { int m = (lo2 + hi2) >> 1; if (batch[m] < g + 1) lo2 = m + 1; else hi2 = m; }
    int cnt = lo2 - lo;
    float acc = 0.f;
    int n = lo + rg;
    for (; n + 24 < lo2; n += 32) {
        float u0 = p[n * 32 + d];
        float u1 = p[(n + 8) * 32 + d];
        float u2 = p[(n + 16) * 32 + d];
        float u3 = p[(n + 24) * 32 + d];
        acc += (u0 + u1) + (u2 + u3);
    }
    for (; n < lo2; n += 8) acc += p[n * 32 + d];
    partial[rg][d] = acc;
    __syncthreads();
    if (rg == 0) {
        float s = 0.f;
#pragma unroll
        for (int r = 0; r < 8; ++r) s += partial[r][d];
        out[g * 32 + d] = (cnt > 0) ? s / (float)cnt + bc[d] : 0.f;
    }
}

// ---------------- launch ----------------

static inline size_t align_up(size_t x) { return (x + 255) & ~(size_t)255; }

extern "C" void kernel_launch(void* const* d_in, const int* in_sizes, int n_in,
                              void* d_out, int out_size, void* d_ws, size_t ws_size,
                              hipStream_t stream) {
    const float* x = (const float*)d_in[0];
    const int* edge_index = (const int*)d_in[1];
    const int* batch = (const int*)d_in[2];
    const float* W1 = (const float*)d_in[3];
    const float* b1 = (const float*)d_in[4];
    const float* W2 = (const float*)d_in[5];
    const float* b2 = (const float*)d_in[6];
    const float* W3 = (const float*)d_in[7];
    const float* b3 = (const float*)d_in[8];
    const float* W4 = (const float*)d_in[9];
    const float* b4 = (const float*)d_in[10];
    const float* fcW = (const float*)d_in[11];
    const float* fcb = (const float*)d_in[12];
    float* out = (float*)d_out;

    const int* src = edge_index;
    const int* dst = edge_index + N_EDGES;

    char* base = (char*)d_ws;
    size_t o = 0;
    unsigned* buf0 = (unsigned*)(base + o);  o = align_up(o + (size_t)N_NODES * D_OUT * 2);
    unsigned* buf1 = (unsigned*)(base + o);  o = align_up(o + (size_t)N_NODES * D_OUT * 2);
    unsigned* csr4 = (unsigned*)(base + o);  o = align_up(o + (size_t)768000 * 4);
    unsigned short* rank = (unsigned short*)(base + o); o = align_up(o + (size_t)N_EDGES * 2);
    int* row_off = (int*)(base + o);         o = align_up(o + (size_t)(N_NODES + 1) * 4);
    int* indeg = (int*)(base + o);           o = align_up(o + (size_t)N_NODES * 4);
    float* dinv = (float*)(base + o);        o = align_up(o + (size_t)N_NODES * 4);
    unsigned short* WcT = (unsigned short*)(base + o); o = align_up(o + (size_t)D * D_OUT * 2);
    float* cvec = (float*)(base + o);        o = align_up(o + 128 * 4);
    float* p = (float*)(base + o);           o = align_up(o + (size_t)N_NODES * D_OUT * 4);

    prep_kernel<<<50, 1024, 0, stream>>>(indeg, W1, W2, W3, W4, fcW, fcb,
                                         b1, b2, b3, b4, WcT, cvec);
    hist_kernel<<<FILL_BLOCKS, 256, 0, stream>>>(dst, indeg, rank);
    scan_kernel<<<N_SCAN_BLOCKS, 1024, 0, stream>>>(indeg, row_off, dinv, csr4);
    fillgemm_kernel<<<GEMM_TILES + FILL_BLOCKS, 256, 0, stream>>>(
        x, WcT, (uint4*)buf0, src, dst, row_off, rank, dinv, csr4);

    agg_kernel<false><<<AGG_GRID, 256, 0, stream>>>(buf0, cvec + 0, dinv, row_off,
                                                    csr4, buf1, nullptr);
    agg_kernel<false><<<AGG_GRID, 256, 0, stream>>>(buf1, cvec + 32, dinv, row_off,
                                                    csr4, buf0, nullptr);
    agg_kernel<false><<<AGG_GRID, 256, 0, stream>>>(buf0, cvec + 64, dinv, row_off,
                                                    csr4, buf1, nullptr);
    agg_kernel<true><<<AGG_GRID, 256, 0, stream>>>(buf1, nullptr, dinv, row_off,
                                                   csr4, nullptr, p);
    tail_kernel<<<N_GRAPHS, 256, 0, stream>>>(p, batch, cvec + 96, out);
}